// Round 15
// baseline (211.608 us; speedup 1.0000x reference)
//
#include <hip/hip_runtime.h>
#include <cstddef>

#define D    64
#define L    128
#define NT   256           // 4 waves per block
#define ROWS 8             // rows per block (half-filled M=16 MFMA tile)
#define XSS  132           // padded floats
#define HBS  72            // shorts
#define NBLK 1024          // 8192 / 8
#define NREP 64            // atomic replica bins
#define LOG2E 1.4426950408889634f

// ws float offsets
#define WS_REP    0                    // 64 bins x 128 floats
#define WS_TICKET (NREP * 2 * D)       // 8192
#define WS_AN     (WS_TICKET + 64)     // 8256: 256 prescaled An
#define WS_BC     (WS_AN + 256)        // 8512: 256 prescaled Bc
#define WS_WHH    (WS_BC + 256)        // 8768: 256x64 bf16 shorts (16B-aligned)

typedef __attribute__((ext_vector_type(8))) short short8;
typedef __attribute__((ext_vector_type(4))) float floatx4;
typedef __attribute__((ext_vector_type(2))) float f2;

__device__ __forceinline__ float fast_rcp(float x) {
#if defined(__has_builtin)
#if __has_builtin(__builtin_amdgcn_rcpf)
  return __builtin_amdgcn_rcpf(x);
#else
  return 1.0f / x;
#endif
#else
  return 1.0f / x;
#endif
}
__device__ __forceinline__ float ex2(float x) {
#if defined(__has_builtin)
#if __has_builtin(__builtin_amdgcn_exp2f)
  return __builtin_amdgcn_exp2f(x);
#else
  return __builtin_exp2f(x);
#endif
#else
  return __builtin_exp2f(x);
#endif
}
__device__ __forceinline__ f2 ex2_2(f2 v) { return (f2){ex2(v.x), ex2(v.y)}; }
__device__ __forceinline__ f2 rcp_2(f2 v) { return (f2){fast_rcp(v.x), fast_rcp(v.y)}; }
__device__ __forceinline__ float sig_plain(float x) {
  return fast_rcp(1.0f + ex2(-LOG2E * x));
}
__device__ __forceinline__ float tanh2(float G) {   // tanh(x), G = -2log2e*x
  return fmaf(2.0f, fast_rcp(1.0f + ex2(G)), -1.0f);
}
__device__ __forceinline__ unsigned short f2bf_rtne(float f) {
  unsigned int u = __float_as_uint(f);
  u += 0x7fffu + ((u >> 16) & 1u);
  return (unsigned short)(u >> 16);
}

// Setup: per gate-column j, precompute prescaled rank-1 constants An/Bc and
// prescaled single-bf16 W_hh. Removes the per-block scatter-read preamble
// that caused R9's 27 MB fetch storm (1024 blocks re-reading W_ih/W_hh).
__global__ void lstm_setup(const float* __restrict__ W_num,
                           const float* __restrict__ b_num,
                           const float* __restrict__ W_ih,
                           const float* __restrict__ W_hh,
                           const float* __restrict__ b_ih,
                           const float* __restrict__ b_hh,
                           float* __restrict__ ws)
{
  const int j = blockIdx.x * 64 + threadIdx.x;   // 0..255
  const int g = j >> 6;
  const float gs = (g == 2) ? (-2.0f * LOG2E) : (-LOG2E);
  float a = 0.0f, b = b_ih[j] + b_hh[j];
  const float* wr = W_ih + (size_t)j * (2 * D);
  for (int e = 0; e < D; ++e) {
    a = fmaf(W_num[e], wr[e], a);
    b = fmaf(b_num[e], wr[e], b);
  }
  ws[WS_AN + j] = a * gs;
  ws[WS_BC + j] = b * gs;
  unsigned short* whh = (unsigned short*)(ws + WS_WHH);
  const float* wh = W_hh + (size_t)j * D;
  for (int e = 0; e < D; ++e)
    whh[j * D + e] = f2bf_rtne(wh[e] * gs);
}

// Persistent 8-row LSTM scan: R9 topology (1024 blocks x 4 waves = 4
// blocks/CU, 4 waves/SIMD — double R11's convoy fill) with the traffic
// pathologies fixed (setup kernel for weights; 64 replica atomic bins).
// Half-filled M=16 tile: real row q*2+r at tile-row q*4+r (r=0,1); tile-rows
// ==2,3 mod 4 stay zero in hb. Wave w owns d in [16w,16w+16) for all 4
// gates -> gates register-resident, ONE barrier/step; single-bf16 W_hh =
// 8 MFMAs/wave/step (CU matrix pipe 620 cyc/step at 4.85 cyc/MFMA, shared);
// packed-fp32 elementwise, merged 5-exp2/2-rcp algebra, 2 cells/lane.
__global__ __launch_bounds__(NT, 4)
void lstm_main(const float* __restrict__ x,
               const float* __restrict__ W_aout,
               const float* __restrict__ b_aout,
               const float* __restrict__ W_fh,
               const float* __restrict__ b_fh,
               const float* __restrict__ W_iouh,
               const float* __restrict__ b_iouh,
               const float* __restrict__ W_oout,
               const float* __restrict__ b_oout,
               float* __restrict__ ws,
               float* __restrict__ out)
{
  __shared__ __align__(16) float xs[ROWS * XSS];       // 4.1 KB (x; later h/h_hat)
  __shared__ __align__(16) short hb[2][16 * HBS];      // 4.5 KB double-buffered bf16 h
  __shared__ float sacc[2 * D];
  __shared__ float hobj[D];
  __shared__ int   is_last;

  const int tid  = threadIdx.x;
  const int w    = tid >> 6;
  const int lane = tid & 63;
  const int quad = lane >> 4;
  const int c16  = lane & 15;
  const int k0   = blockIdx.x * ROWS;
  const int dcol = w * 16 + c16;

  // ---- stage x tile (8 rows x 128), coalesced; zero BOTH hb buffers ----
  {
    int i = tid;                       // exactly ROWS*(L/4) == NT elements
    int r = i >> 5, c4 = i & 31;
    float4 v = ((const float4*)(x + (size_t)(k0 + r) * L))[c4];
    float* dst = &xs[r * XSS + c4 * 4];
    dst[0] = v.x; dst[1] = v.y; dst[2] = v.z; dst[3] = v.w;
  }
  for (int i = tid; i < 2 * 16 * HBS; i += NT) (&hb[0][0])[i] = 0;

  // ---- load precomputed constants ----
  float An[4], Bc[4];
  short8 Bf[4][2];
  const unsigned short* whh = (const unsigned short*)(ws + WS_WHH);
#pragma unroll
  for (int g = 0; g < 4; ++g) {
    int j = g * 64 + dcol;
    An[g] = ws[WS_AN + j];
    Bc[g] = ws[WS_BC + j];
#pragma unroll
    for (int kk = 0; kk < 2; ++kk)
      Bf[g][kk] = *(const short8*)&whh[j * D + kk * 32 + quad * 8];
  }

  const f2 one2 = {1.0f, 1.0f};
  const f2 m2l2 = {-2.0f * LOG2E, -2.0f * LOG2E};
  f2 creg2 = {0.f, 0.f};   // cells rows quad*2 + {0,1}, d=dcol
  f2 hreg2 = {0.f, 0.f};
  __syncthreads();

  int p = 0;
  for (int t4 = 0; t4 < L; t4 += 4) {
    float4 xq0 = *(const float4*)&xs[(quad * 2 + 0) * XSS + t4];
    float4 xq1 = *(const float4*)&xs[(quad * 2 + 1) * XSS + t4];
#pragma unroll
    for (int u = 0; u < 4; ++u) {
      // A-fragment of h(t-1): tile-rows ==2,3 mod 4 are zero
      short8 ahi[2];
#pragma unroll
      for (int kk = 0; kk < 2; ++kk)
        ahi[kk] = *(const short8*)&hb[p][c16 * HBS + kk * 32 + quad * 8];
      f2 xv = {xq0[u], xq1[u]};
      floatx4 acc[4];
#pragma unroll
      for (int g = 0; g < 4; ++g) {
        f2 A2 = {An[g], An[g]}, B2 = {Bc[g], Bc[g]};
        f2 i01 = A2 * xv + B2;          // v_pk_fma_f32
        acc[g] = (floatx4){i01.x, i01.y, 0.0f, 0.0f};   // regs 2,3 unused
      }
#pragma unroll
      for (int kk = 0; kk < 2; ++kk) {
#pragma unroll
        for (int g = 0; g < 4; ++g)
          acc[g] = __builtin_amdgcn_mfma_f32_16x16x32_bf16(ahi[kk], Bf[g][kk], acc[g], 0, 0, 0);
      }
      // merged elementwise: one packed cell-pair per lane
      {
        f2 Gi = {acc[0][0], acc[0][1]};
        f2 Gf = {acc[1][0], acc[1][1]};
        f2 Gg = {acc[2][0], acc[2][1]};
        f2 Go = {acc[3][0], acc[3][1]};
        f2 Ei = ex2_2(Gi), Ef = ex2_2(Gf), Eg = ex2_2(Gg), Eo = ex2_2(Go);
        f2 pf = Ef + one2, pi = Ei + one2, pg = Eg + one2, mg = one2 - Eg;
        f2 pig = pi * pg;
        f2 num = creg2 * pig + mg * pf;
        f2 c2  = num * rcp_2(pf * pig);
        creg2 = c2;
        f2 Ec = ex2_2(c2 * m2l2);
        f2 po = Eo + one2, pc = Ec + one2, mc = one2 - Ec;
        f2 h2 = mc * rcp_2(po * pc);
        hreg2 = h2;
        hb[p ^ 1][(quad * 4 + 0) * HBS + dcol] = (short)f2bf_rtne(h2.x);
        hb[p ^ 1][(quad * 4 + 1) * HBS + dcol] = (short)f2bf_rtne(h2.y);
      }
      __syncthreads();
      p ^= 1;
    }
  }

  // ---- tail: h_hat = h@W_aout.T+b ; f = h_hat@W_fh.T+b ; partial sums ----
  xs[(quad * 2 + 0) * XSS + dcol] = hreg2.x;
  xs[(quad * 2 + 1) * XSS + dcol] = hreg2.y;
  __syncthreads();

  float hhat[2];
#pragma unroll
  for (int r = 0; r < 2; ++r) {
    float a = b_aout[dcol];
    const float4* wa = (const float4*)(W_aout + (size_t)dcol * D);
    const float* hp = &xs[(quad * 2 + r) * XSS];
#pragma unroll
    for (int e4 = 0; e4 < 16; ++e4) {
      float4 wv = wa[e4];
      a = fmaf(wv.x, hp[e4*4+0], a); a = fmaf(wv.y, hp[e4*4+1], a);
      a = fmaf(wv.z, hp[e4*4+2], a); a = fmaf(wv.w, hp[e4*4+3], a);
    }
    hhat[r] = a;
  }
  __syncthreads();
#pragma unroll
  for (int r = 0; r < 2; ++r) xs[(quad * 2 + r) * XSS + 64 + dcol] = hhat[r];
  __syncthreads();

  float pfc = 0.0f, phs = 0.0f;
#pragma unroll
  for (int r = 0; r < 2; ++r) {
    float f = b_fh[dcol];
    const float4* wf = (const float4*)(W_fh + (size_t)dcol * D);
    const float* hp = &xs[(quad * 2 + r) * XSS + 64];
#pragma unroll
    for (int e4 = 0; e4 < 16; ++e4) {
      float4 wv = wf[e4];
      f = fmaf(wv.x, hp[e4*4+0], f); f = fmaf(wv.y, hp[e4*4+1], f);
      f = fmaf(wv.z, hp[e4*4+2], f); f = fmaf(wv.w, hp[e4*4+3], f);
    }
    float cc = r ? creg2.y : creg2.x;
    pfc = fmaf(sig_plain(f), cc, pfc);
    phs += hhat[r];
  }
  // reduce over quads (rows), one atomic per dcol into this block's bin
  pfc += __shfl_xor(pfc, 16); pfc += __shfl_xor(pfc, 32);
  phs += __shfl_xor(phs, 16); phs += __shfl_xor(phs, 32);
  float* rep = ws + WS_REP + (blockIdx.x & (NREP - 1)) * (2 * D);
  if (quad == 0) {
    atomicAdd(rep + dcol, pfc);
    atomicAdd(rep + D + dcol, phs);
  }

  // ---- last-block finish ----
  __threadfence();
  if (tid == 0) {
    unsigned int prev = __hip_atomic_fetch_add((unsigned int*)(ws + WS_TICKET), 1u,
                                               __ATOMIC_ACQ_REL, __HIP_MEMORY_SCOPE_AGENT);
    is_last = (prev == NBLK - 1) ? 1 : 0;
  }
  __syncthreads();
  if (!is_last) return;
  __threadfence();
  if (tid < 2 * D) {
    float s = 0.0f;
    for (int rp = 0; rp < NREP; ++rp)
      s += __hip_atomic_load(ws + WS_REP + rp * (2 * D) + tid,
                             __ATOMIC_RELAXED, __HIP_MEMORY_SCOPE_AGENT);
    sacc[tid] = s;
  }
  __syncthreads();
  if (tid < D) {
    const int d = tid;
    float vi = b_iouh[d], vo = b_iouh[D + d], vu = b_iouh[2 * D + d];
    for (int e = 0; e < D; ++e) {
      float hs = sacc[D + e];
      vi = fmaf(W_iouh[(size_t)d * D + e],           hs, vi);
      vo = fmaf(W_iouh[(size_t)(D + d) * D + e],     hs, vo);
      vu = fmaf(W_iouh[(size_t)(2 * D + d) * D + e], hs, vu);
    }
    float c_obj = sig_plain(vi) * tanh2(-2.0f * LOG2E * vu) + sacc[d];
    float h_obj = sig_plain(vo) * tanh2(-2.0f * LOG2E * c_obj);
    hobj[d] = h_obj;
    out[D + d] = c_obj;
  }
  __syncthreads();
  if (tid < D) {
    const int d = tid;
    float hh = b_oout[d];
    for (int e = 0; e < D; ++e) hh = fmaf(W_oout[(size_t)d * D + e], hobj[e], hh);
    out[d] = hh;
  }
}

extern "C" void kernel_launch(void* const* d_in, const int* in_sizes, int n_in,
                              void* d_out, int out_size, void* d_ws, size_t ws_size,
                              hipStream_t stream) {
  const float* x      = (const float*)d_in[0];
  const float* W_num  = (const float*)d_in[1];
  const float* b_num  = (const float*)d_in[2];
  const float* W_ih   = (const float*)d_in[3];
  const float* W_hh   = (const float*)d_in[4];
  const float* b_ih   = (const float*)d_in[5];
  const float* b_hh   = (const float*)d_in[6];
  const float* W_aout = (const float*)d_in[7];
  const float* b_aout = (const float*)d_in[8];
  const float* W_fh   = (const float*)d_in[9];
  const float* b_fh   = (const float*)d_in[10];
  const float* W_iouh = (const float*)d_in[11];
  const float* b_iouh = (const float*)d_in[12];
  const float* W_oout = (const float*)d_in[13];
  const float* b_oout = (const float*)d_in[14];
  float* ws  = (float*)d_ws;
  float* out = (float*)d_out;

  // zero replica bins + ticket (AN/BC/WHH fully overwritten by lstm_setup)
  hipMemsetAsync(d_ws, 0, (WS_TICKET + 4) * sizeof(float), stream);
  lstm_setup<<<4, 64, 0, stream>>>(W_num, b_num, W_ih, W_hh, b_ih, b_hh, ws);
  lstm_main<<<NBLK, NT, 0, stream>>>(x, W_aout, b_aout, W_fh, b_fh,
                                     W_iouh, b_iouh, W_oout, b_oout, ws, out);
}